// Round 8
// baseline (370.267 us; speedup 1.0000x reference)
//
#include <hip/hip_runtime.h>

#define NN 2048
#define DD 512
#define MM 8
#define GRAM_BLOCKS 2048

typedef __attribute__((ext_vector_type(8))) short short8_t;   // 8 x bf16 bits (4 VGPR)
typedef __attribute__((ext_vector_type(4))) float f32x4_t;    // MFMA 16x16 accumulator

#define AS1 __attribute__((address_space(1)))
#define AS3 __attribute__((address_space(3)))

__host__ __device__ constexpr int tri_idx(int m, int mm) {
    return m * 8 - m * (m + 1) / 2 + mm;   // upper-tri packed index, 8x8 -> 36
}

__device__ inline unsigned short f2bf_rne(float f) {
    unsigned int u = __float_as_uint(f);
    u += 0x7FFFu + ((u >> 16) & 1u);       // round-to-nearest-even
    return (unsigned short)(u >> 16);
}
__device__ inline float bf2f(unsigned short h) {
    return __uint_as_float(((unsigned int)h) << 16);
}

// ---------------------------------------------------------------------------
// Kernel 0: split X (fp32 [NN][DD]) into Xhi + Xlo (bf16 bit patterns).
// Block 0 also zeroes gram's last-block-done counter (stream-ordered before
// gram_kernel; must happen every call — buffers are poisoned, not restored).
// ---------------------------------------------------------------------------
__global__ __launch_bounds__(256) void convert_split(const float* __restrict__ X,
                                                     unsigned short* __restrict__ Xhi,
                                                     unsigned short* __restrict__ Xlo,
                                                     int* __restrict__ counter) {
    if (blockIdx.x == 0 && threadIdx.x == 0) *counter = 0;
    const int idx = (blockIdx.x * 256 + threadIdx.x) * 4;   // 1024 blocks covers NN*DD exactly
    float4 v = *reinterpret_cast<const float4*>(&X[idx]);
    float xs[4] = {v.x, v.y, v.z, v.w};
    ushort4 hi, lo;
    unsigned short* hp = &hi.x;
    unsigned short* lp = &lo.x;
    #pragma unroll
    for (int j = 0; j < 4; ++j) {
        unsigned short h = f2bf_rne(xs[j]);
        hp[j] = h;
        lp[j] = f2bf_rne(xs[j] - bf2f(h));
    }
    *reinterpret_cast<ushort4*>(&Xhi[idx]) = hi;
    *reinterpret_cast<ushort4*>(&Xlo[idx]) = lo;
}

// ---------------------------------------------------------------------------
// Kernel 1: Y = Xhi Xhi^T + Xhi Xlo^T + Xlo Xhi^T  via 16x16x32 bf16 MFMA.
// 128x128 tile, BK=32, 256 threads = 4 waves (2x2 of 64x64), grid 16x16.
// DOUBLE-BUFFERED staging (T3 minimum 2-phase): stage(t+1) issued before
// consuming tile t; the single end-of-iter barrier drains it. At 1 block/CU
// there is no inter-block overlap, so this is the only latency hiding.
// ---------------------------------------------------------------------------
__global__ __launch_bounds__(256) void gemm_mfma(const unsigned short* __restrict__ Xhi,
                                                 const unsigned short* __restrict__ Xlo,
                                                 float* __restrict__ Y) {
    __shared__ unsigned short lds[2][4 * 128 * 32];   // 2 stage sets x 32 KB

    const int tid = threadIdx.x;
    const int lane = tid & 63;
    const int wave = tid >> 6;
    const int wr = wave >> 1;            // wave row 0..1
    const int wc = wave & 1;             // wave col 0..1
    const int rowBase = blockIdx.y * 128;
    const int colBase = blockIdx.x * 128;

    f32x4_t acc[4][4] = {};

    const int r = lane & 15;             // fragment row within 16
    const int gq = lane >> 4;            // k-chunk 0..3 (8 bf16 each)

    auto stage = [&](int d, int k0) {
        unsigned short* base = &lds[d][0];
        #pragma unroll
        for (int i = 0; i < 2; ++i) {
            const int gc = i * 256 + tid;          // chunk index 0..511
            const int row = gc >> 2;
            const int g = gc & 3;
            const int gsrc = g ^ ((row >> 1) & 3); // pre-swizzled source chunk
            const unsigned short* gA  = &Xhi[(rowBase + row) * DD + k0 + gsrc * 8];
            const unsigned short* gAl = &Xlo[(rowBase + row) * DD + k0 + gsrc * 8];
            const unsigned short* gB  = &Xhi[(colBase + row) * DD + k0 + gsrc * 8];
            const unsigned short* gBl = &Xlo[(colBase + row) * DD + k0 + gsrc * 8];
            const int lbase = (i * 256 + wave * 64) * 8;   // wave-uniform LDS base (ushorts)
            __builtin_amdgcn_global_load_lds((const AS1 unsigned int*)gA,
                                             (AS3 unsigned int*)(base + 0 + lbase), 16, 0, 0);
            __builtin_amdgcn_global_load_lds((const AS1 unsigned int*)gAl,
                                             (AS3 unsigned int*)(base + 4096 + lbase), 16, 0, 0);
            __builtin_amdgcn_global_load_lds((const AS1 unsigned int*)gB,
                                             (AS3 unsigned int*)(base + 8192 + lbase), 16, 0, 0);
            __builtin_amdgcn_global_load_lds((const AS1 unsigned int*)gBl,
                                             (AS3 unsigned int*)(base + 12288 + lbase), 16, 0, 0);
        }
    };

    stage(0, 0);
    __syncthreads();                     // compiler drains vmcnt(0) before barrier

    for (int t = 0; t < 16; ++t) {
        const int cur = t & 1;
        if (t < 15) stage(cur ^ 1, (t + 1) * 32);   // prefetch next tile into other set

        const unsigned short* base = &lds[cur][0];
        short8_t ah[4], al[4], bh[4], bl[4];
        #pragma unroll
        for (int m = 0; m < 4; ++m) {
            const int row = wr * 64 + m * 16 + r;
            const int off = row * 32 + ((gq ^ ((row >> 1) & 3)) * 8);
            ah[m] = *reinterpret_cast<const short8_t*>(&base[0 + off]);
            al[m] = *reinterpret_cast<const short8_t*>(&base[4096 + off]);
        }
        #pragma unroll
        for (int n = 0; n < 4; ++n) {
            const int row = wc * 64 + n * 16 + r;
            const int off = row * 32 + ((gq ^ ((row >> 1) & 3)) * 8);
            bh[n] = *reinterpret_cast<const short8_t*>(&base[8192 + off]);
            bl[n] = *reinterpret_cast<const short8_t*>(&base[12288 + off]);
        }
        #pragma unroll
        for (int m = 0; m < 4; ++m) {
            #pragma unroll
            for (int n = 0; n < 4; ++n) {
                acc[m][n] = __builtin_amdgcn_mfma_f32_16x16x32_bf16(ah[m], bh[n], acc[m][n], 0, 0, 0);
                acc[m][n] = __builtin_amdgcn_mfma_f32_16x16x32_bf16(ah[m], bl[n], acc[m][n], 0, 0, 0);
                acc[m][n] = __builtin_amdgcn_mfma_f32_16x16x32_bf16(al[m], bh[n], acc[m][n], 0, 0, 0);
            }
        }
        __syncthreads();                 // drains stage(t+1); all reads of cur done
    }

    // C/D layout (m89-verified): col = lane&15, row = (lane>>4)*4 + reg
    #pragma unroll
    for (int m = 0; m < 4; ++m) {
        #pragma unroll
        for (int n = 0; n < 4; ++n) {
            #pragma unroll
            for (int j = 0; j < 4; ++j) {
                const int rr = rowBase + wr * 64 + m * 16 + gq * 4 + j;
                const int cc = colBase + wc * 64 + n * 16 + r;
                Y[rr * NN + cc] = acc[m][n][j];
            }
        }
    }
}

// ---------------------------------------------------------------------------
// Kernel 2: G0 (36) + s0 (8) partials, one 144MB pass, 2048 blocks.
// Blocked-contiguous partition (block b owns p in [b*512, b*512+512)) —
// verified win (16MB-stride alias decorrelation).
// Tail: last-block-done reduction (1 atomic per block, fenced) replaces the
// separate gram_reduce launch. Deterministic: fixed summation tree.
// ---------------------------------------------------------------------------
__global__ __launch_bounds__(256) void gram_kernel(const float* __restrict__ A,
                                                   const float* __restrict__ Y,
                                                   float* __restrict__ partialT,
                                                   float* __restrict__ acc,
                                                   int* __restrict__ counter) {
    const int P4 = (NN * NN) / 4;
    float vals[44];
    #pragma unroll
    for (int i = 0; i < 44; ++i) vals[i] = 0.f;

    const float4* Y4 = reinterpret_cast<const float4*>(Y);
    const float4* A4 = reinterpret_cast<const float4*>(A);
    const int base = blockIdx.x * 512 + threadIdx.x;

    #pragma unroll
    for (int it = 0; it < 2; ++it) {
        const int p = base + it * 256;
        float4 y = Y4[p];
        float4 a[MM];
        #pragma unroll
        for (int m = 0; m < MM; ++m) a[m] = A4[m * P4 + p];
        #pragma unroll
        for (int m = 0; m < MM; ++m) {
            vals[36 + m] += a[m].x * y.x + a[m].y * y.y + a[m].z * y.z + a[m].w * y.w;
            #pragma unroll
            for (int mm = m; mm < MM; ++mm) {
                vals[tri_idx(m, mm)] += a[m].x * a[mm].x + a[m].y * a[mm].y +
                                        a[m].z * a[mm].z + a[m].w * a[mm].w;
            }
        }
    }

    #pragma unroll
    for (int i = 0; i < 44; ++i) {
        float v = vals[i];
        #pragma unroll
        for (int off = 32; off > 0; off >>= 1) v += __shfl_down(v, off);
        vals[i] = v;
    }

    __shared__ float wsum[4][44];
    const int lane = threadIdx.x & 63;
    const int wv = threadIdx.x >> 6;
    if (lane == 0) {
        #pragma unroll
        for (int i = 0; i < 44; ++i) wsum[wv][i] = vals[i];
    }
    __syncthreads();
    if (threadIdx.x < 44) {
        float s = wsum[0][threadIdx.x] + wsum[1][threadIdx.x] +
                  wsum[2][threadIdx.x] + wsum[3][threadIdx.x];
        partialT[threadIdx.x * GRAM_BLOCKS + blockIdx.x] = s;   // transposed, no contention
    }

    // ---- last-block-done reduction (replaces gram_reduce kernel) ----
    __shared__ int amLast;
    __threadfence();                                  // publish partialT stores
    if (threadIdx.x == 0)
        amLast = (atomicAdd(counter, 1) == GRAM_BLOCKS - 1) ? 1 : 0;
    __syncthreads();
    if (amLast) {
        __threadfence();                              // acquire other blocks' stores
        // 4 waves x 11 values, lane-strided coalesced reads (round-5-proven shape)
        #pragma unroll
        for (int q = 0; q < 11; ++q) {
            const int v = wv * 11 + q;
            float s = 0.f;
            for (int b = lane; b < GRAM_BLOCKS; b += 64)
                s += partialT[v * GRAM_BLOCKS + b];
            #pragma unroll
            for (int off = 32; off > 0; off >>= 1) s += __shfl_down(s, off);
            if (lane == 0) acc[v] = s;
        }
    }
}

// ---------------------------------------------------------------------------
// Kernel 3: K deflation iterations in 9-dim coefficient space (fp64).
// Fully unrolled -> G/T/vectors in VGPRs. 64 threads, launch_bounds(64,1)
// so the allocator has the full 512-VGPR budget (proven no-spill config).
// ---------------------------------------------------------------------------
__global__ __launch_bounds__(64, 1) void iterate_kernel(const float* __restrict__ acc,
                                                        const int* __restrict__ Kp,
                                                        float* __restrict__ w_out) {
    double G[MM][MM], s0[MM], T[MM][MM], w[MM];
    #pragma unroll
    for (int m = 0; m < MM; ++m) {
        #pragma unroll
        for (int mm = m; mm < MM; ++mm) {
            double v = (double)acc[tri_idx(m, mm)];
            G[m][mm] = v;
            G[mm][m] = v;
        }
    }
    #pragma unroll
    for (int m = 0; m < MM; ++m) s0[m] = (double)acc[36 + m];
    #pragma unroll
    for (int m = 0; m < MM; ++m) {
        w[m] = 0.0;
        #pragma unroll
        for (int k = 0; k < MM; ++k) T[m][k] = (m == k) ? 1.0 : 0.0;
    }

    const int K = *Kp;
    for (int it = 0; it < K; ++it) {
        double sy[MM];
        #pragma unroll
        for (int k = 0; k < MM; ++k) {
            double a = s0[k];
            #pragma unroll
            for (int j = 0; j < MM; ++j) a += G[k][j] * w[j];
            sy[k] = a;
        }
        double s[MM];
        #pragma unroll
        for (int m = 0; m < MM; ++m) {
            double a = 0.0;
            #pragma unroll
            for (int k = 0; k < MM; ++k) a += T[m][k] * sy[k];
            s[m] = a;
        }
        double c[MM];
        #pragma unroll
        for (int k = 0; k < MM; ++k) {
            double a = 0.0;
            #pragma unroll
            for (int m = 0; m < MM; ++m) a += T[m][k] * s[m];
            c[k] = a;
        }
        double Gc[MM];
        #pragma unroll
        for (int k = 0; k < MM; ++k) {
            double a = 0.0;
            #pragma unroll
            for (int j = 0; j < MM; ++j) a += G[k][j] * c[j];
            Gc[k] = a;
        }
        double den = 0.0, num = 0.0;
        #pragma unroll
        for (int k = 0; k < MM; ++k) den += c[k] * Gc[k];
        #pragma unroll
        for (int m = 0; m < MM; ++m) num += s[m] * s[m];
        const double inv_den = 1.0 / den;
        const double alpha = num * inv_den;
        #pragma unroll
        for (int k = 0; k < MM; ++k) w[k] -= alpha * c[k];
        #pragma unroll
        for (int m = 0; m < MM; ++m) {
            double beta = 0.0;
            #pragma unroll
            for (int k = 0; k < MM; ++k) beta += T[m][k] * Gc[k];
            beta *= inv_den;
            #pragma unroll
            for (int k = 0; k < MM; ++k) T[m][k] -= beta * c[k];
        }
    }
    if (threadIdx.x == 0 && blockIdx.x == 0) {
        #pragma unroll
        for (int k = 0; k < MM; ++k) w_out[k] = (float)w[k];
    }
}

// ---------------------------------------------------------------------------
// Kernel 4: Y += sum_m w_m * A0_m (in place on d_out).
// Same blocked-contiguous partition as gram.
// ---------------------------------------------------------------------------
__global__ __launch_bounds__(256) void reconstruct(const float* __restrict__ A,
                                                   const float* __restrict__ w,
                                                   float* __restrict__ Y) {
    __shared__ float wsh[MM];
    if (threadIdx.x < MM) wsh[threadIdx.x] = w[threadIdx.x];
    __syncthreads();
    float wl[MM];
    #pragma unroll
    for (int m = 0; m < MM; ++m) wl[m] = wsh[m];

    const int P4 = (NN * NN) / 4;
    float4* Y4 = reinterpret_cast<float4*>(Y);
    const float4* A4 = reinterpret_cast<const float4*>(A);
    const int base = blockIdx.x * 512 + threadIdx.x;

    #pragma unroll
    for (int it = 0; it < 2; ++it) {
        const int p = base + it * 256;
        float4 y = Y4[p];
        #pragma unroll
        for (int m = 0; m < MM; ++m) {
            float4 a = A4[m * P4 + p];
            y.x += wl[m] * a.x;
            y.y += wl[m] * a.y;
            y.z += wl[m] * a.z;
            y.w += wl[m] * a.w;
        }
        Y4[p] = y;
    }
}

extern "C" void kernel_launch(void* const* d_in, const int* in_sizes, int n_in,
                              void* d_out, int out_size, void* d_ws, size_t ws_size,
                              hipStream_t stream) {
    const float* X = (const float*)d_in[0];
    const float* A = (const float*)d_in[1];
    const int* Kp = (const int*)d_in[2];
    float* Y = (float*)d_out;

    float* acc = (float*)d_ws;                                 // [0..43]  G0 tri + s0
    int* counter = (int*)d_ws + 46;                            // last-block-done counter
    float* w = (float*)d_ws + 48;                              // [48..55] w coefficients
    unsigned short* Xhi = (unsigned short*)((char*)d_ws + 4096);
    unsigned short* Xlo = Xhi + NN * DD;                       // 2 MB each
    float* partialT = (float*)((char*)d_ws + (8u << 20));      // [44][2048] floats

    convert_split<<<1024, 256, 0, stream>>>(X, Xhi, Xlo, counter);
    gemm_mfma<<<dim3(16, 16), 256, 0, stream>>>(Xhi, Xlo, Y);
    gram_kernel<<<GRAM_BLOCKS, 256, 0, stream>>>(A, Y, partialT, acc, counter);
    iterate_kernel<<<1, 64, 0, stream>>>(acc, Kp, w);
    reconstruct<<<2048, 256, 0, stream>>>(A, w, Y);
}

// Round 9
// 101.563 us; speedup vs baseline: 3.6457x; 3.6457x over previous
//
#include <hip/hip_runtime.h>

#define NN 2048
#define DD 512
#define MM 8
#define GRAM_BLOCKS 2048

typedef __attribute__((ext_vector_type(8))) short short8_t;   // 8 x bf16 bits (4 VGPR)
typedef __attribute__((ext_vector_type(4))) float f32x4_t;    // MFMA 16x16 accumulator

#define AS1 __attribute__((address_space(1)))
#define AS3 __attribute__((address_space(3)))

__host__ __device__ constexpr int tri_idx(int m, int mm) {
    return m * 8 - m * (m + 1) / 2 + mm;   // upper-tri packed index, 8x8 -> 36
}

__device__ inline unsigned short f2bf_rne(float f) {
    unsigned int u = __float_as_uint(f);
    u += 0x7FFFu + ((u >> 16) & 1u);       // round-to-nearest-even
    return (unsigned short)(u >> 16);
}
__device__ inline float bf2f(unsigned short h) {
    return __uint_as_float(((unsigned int)h) << 16);
}

// ---------------------------------------------------------------------------
// Kernel 0: split X (fp32 [NN][DD]) into Xhi + Xlo (bf16 bit patterns).
// ---------------------------------------------------------------------------
__global__ __launch_bounds__(256) void convert_split(const float* __restrict__ X,
                                                     unsigned short* __restrict__ Xhi,
                                                     unsigned short* __restrict__ Xlo) {
    const int idx = (blockIdx.x * 256 + threadIdx.x) * 4;   // 1024 blocks covers NN*DD exactly
    float4 v = *reinterpret_cast<const float4*>(&X[idx]);
    float xs[4] = {v.x, v.y, v.z, v.w};
    ushort4 hi, lo;
    unsigned short* hp = &hi.x;
    unsigned short* lp = &lo.x;
    #pragma unroll
    for (int j = 0; j < 4; ++j) {
        unsigned short h = f2bf_rne(xs[j]);
        hp[j] = h;
        lp[j] = f2bf_rne(xs[j] - bf2f(h));
    }
    *reinterpret_cast<ushort4*>(&Xhi[idx]) = hi;
    *reinterpret_cast<ushort4*>(&Xlo[idx]) = lo;
}

// ---------------------------------------------------------------------------
// Kernel 1: Y = Xhi Xhi^T + Xhi Xlo^T + Xlo Xhi^T  via 16x16x32 bf16 MFMA.
// 128x128 tile, BK=32, 256 threads = 4 waves (2x2 of 64x64), grid 16x16.
// Double-buffered staging: stage(t+1) issued before consuming tile t.
// ---------------------------------------------------------------------------
__global__ __launch_bounds__(256) void gemm_mfma(const unsigned short* __restrict__ Xhi,
                                                 const unsigned short* __restrict__ Xlo,
                                                 float* __restrict__ Y) {
    __shared__ unsigned short lds[2][4 * 128 * 32];   // 2 stage sets x 32 KB

    const int tid = threadIdx.x;
    const int lane = tid & 63;
    const int wave = tid >> 6;
    const int wr = wave >> 1;            // wave row 0..1
    const int wc = wave & 1;             // wave col 0..1
    const int rowBase = blockIdx.y * 128;
    const int colBase = blockIdx.x * 128;

    f32x4_t acc[4][4] = {};

    const int r = lane & 15;             // fragment row within 16
    const int gq = lane >> 4;            // k-chunk 0..3 (8 bf16 each)

    auto stage = [&](int d, int k0) {
        unsigned short* base = &lds[d][0];
        #pragma unroll
        for (int i = 0; i < 2; ++i) {
            const int gc = i * 256 + tid;          // chunk index 0..511
            const int row = gc >> 2;
            const int g = gc & 3;
            const int gsrc = g ^ ((row >> 1) & 3); // pre-swizzled source chunk
            const unsigned short* gA  = &Xhi[(rowBase + row) * DD + k0 + gsrc * 8];
            const unsigned short* gAl = &Xlo[(rowBase + row) * DD + k0 + gsrc * 8];
            const unsigned short* gB  = &Xhi[(colBase + row) * DD + k0 + gsrc * 8];
            const unsigned short* gBl = &Xlo[(colBase + row) * DD + k0 + gsrc * 8];
            const int lbase = (i * 256 + wave * 64) * 8;   // wave-uniform LDS base (ushorts)
            __builtin_amdgcn_global_load_lds((const AS1 unsigned int*)gA,
                                             (AS3 unsigned int*)(base + 0 + lbase), 16, 0, 0);
            __builtin_amdgcn_global_load_lds((const AS1 unsigned int*)gAl,
                                             (AS3 unsigned int*)(base + 4096 + lbase), 16, 0, 0);
            __builtin_amdgcn_global_load_lds((const AS1 unsigned int*)gB,
                                             (AS3 unsigned int*)(base + 8192 + lbase), 16, 0, 0);
            __builtin_amdgcn_global_load_lds((const AS1 unsigned int*)gBl,
                                             (AS3 unsigned int*)(base + 12288 + lbase), 16, 0, 0);
        }
    };

    stage(0, 0);
    __syncthreads();                     // compiler drains vmcnt(0) before barrier

    for (int t = 0; t < 16; ++t) {
        const int cur = t & 1;
        if (t < 15) stage(cur ^ 1, (t + 1) * 32);   // prefetch next tile into other set

        const unsigned short* base = &lds[cur][0];
        short8_t ah[4], al[4], bh[4], bl[4];
        #pragma unroll
        for (int m = 0; m < 4; ++m) {
            const int row = wr * 64 + m * 16 + r;
            const int off = row * 32 + ((gq ^ ((row >> 1) & 3)) * 8);
            ah[m] = *reinterpret_cast<const short8_t*>(&base[0 + off]);
            al[m] = *reinterpret_cast<const short8_t*>(&base[4096 + off]);
        }
        #pragma unroll
        for (int n = 0; n < 4; ++n) {
            const int row = wc * 64 + n * 16 + r;
            const int off = row * 32 + ((gq ^ ((row >> 1) & 3)) * 8);
            bh[n] = *reinterpret_cast<const short8_t*>(&base[8192 + off]);
            bl[n] = *reinterpret_cast<const short8_t*>(&base[12288 + off]);
        }
        #pragma unroll
        for (int m = 0; m < 4; ++m) {
            #pragma unroll
            for (int n = 0; n < 4; ++n) {
                acc[m][n] = __builtin_amdgcn_mfma_f32_16x16x32_bf16(ah[m], bh[n], acc[m][n], 0, 0, 0);
                acc[m][n] = __builtin_amdgcn_mfma_f32_16x16x32_bf16(ah[m], bl[n], acc[m][n], 0, 0, 0);
                acc[m][n] = __builtin_amdgcn_mfma_f32_16x16x32_bf16(al[m], bh[n], acc[m][n], 0, 0, 0);
            }
        }
        __syncthreads();                 // drains stage(t+1); all reads of cur done
    }

    // C/D layout (m89-verified): col = lane&15, row = (lane>>4)*4 + reg
    #pragma unroll
    for (int m = 0; m < 4; ++m) {
        #pragma unroll
        for (int n = 0; n < 4; ++n) {
            #pragma unroll
            for (int j = 0; j < 4; ++j) {
                const int rr = rowBase + wr * 64 + m * 16 + gq * 4 + j;
                const int cc = colBase + wc * 64 + n * 16 + r;
                Y[rr * NN + cc] = acc[m][n][j];
            }
        }
    }
}

// ---------------------------------------------------------------------------
// Kernel 2: G0 (36) + s0 (8) partials, one 144MB pass, 2048 blocks.
// Blocked-contiguous partition (block b owns p in [b*512, b*512+512)).
// Plain partialT stores ONLY — no fence, no atomic. (Round 8: per-block
// __threadfence() forced 2048 serialized L2 writebacks, 26 -> 377us.)
// ---------------------------------------------------------------------------
__global__ __launch_bounds__(256) void gram_kernel(const float* __restrict__ A,
                                                   const float* __restrict__ Y,
                                                   float* __restrict__ partialT) {
    const int P4 = (NN * NN) / 4;
    float vals[44];
    #pragma unroll
    for (int i = 0; i < 44; ++i) vals[i] = 0.f;

    const float4* Y4 = reinterpret_cast<const float4*>(Y);
    const float4* A4 = reinterpret_cast<const float4*>(A);
    const int base = blockIdx.x * 512 + threadIdx.x;

    #pragma unroll
    for (int it = 0; it < 2; ++it) {
        const int p = base + it * 256;
        float4 y = Y4[p];
        float4 a[MM];
        #pragma unroll
        for (int m = 0; m < MM; ++m) a[m] = A4[m * P4 + p];
        #pragma unroll
        for (int m = 0; m < MM; ++m) {
            vals[36 + m] += a[m].x * y.x + a[m].y * y.y + a[m].z * y.z + a[m].w * y.w;
            #pragma unroll
            for (int mm = m; mm < MM; ++mm) {
                vals[tri_idx(m, mm)] += a[m].x * a[mm].x + a[m].y * a[mm].y +
                                        a[m].z * a[mm].z + a[m].w * a[mm].w;
            }
        }
    }

    #pragma unroll
    for (int i = 0; i < 44; ++i) {
        float v = vals[i];
        #pragma unroll
        for (int off = 32; off > 0; off >>= 1) v += __shfl_down(v, off);
        vals[i] = v;
    }

    __shared__ float wsum[4][44];
    const int lane = threadIdx.x & 63;
    const int wv = threadIdx.x >> 6;
    if (lane == 0) {
        #pragma unroll
        for (int i = 0; i < 44; ++i) wsum[wv][i] = vals[i];
    }
    __syncthreads();
    if (threadIdx.x < 44) {
        float s = wsum[0][threadIdx.x] + wsum[1][threadIdx.x] +
                  wsum[2][threadIdx.x] + wsum[3][threadIdx.x];
        partialT[threadIdx.x * GRAM_BLOCKS + blockIdx.x] = s;   // transposed, no contention
    }
}

// ---------------------------------------------------------------------------
// Kernel 2b: reduce partialT[44][2048] -> acc[44]. 44 blocks, coalesced reads.
// Separate launch on purpose: kernel-boundary gives cross-block visibility
// for free (no per-block device fences); fusing with fp64 iterate spills.
// ---------------------------------------------------------------------------
__global__ __launch_bounds__(256) void gram_reduce(const float* __restrict__ partialT,
                                                   float* __restrict__ acc) {
    const int v = blockIdx.x;            // 0..43
    float s = 0.f;
    for (int b = threadIdx.x; b < GRAM_BLOCKS; b += 256)
        s += partialT[v * GRAM_BLOCKS + b];
    #pragma unroll
    for (int off = 32; off > 0; off >>= 1) s += __shfl_down(s, off);

    __shared__ float wsum[4];
    const int lane = threadIdx.x & 63;
    const int wv = threadIdx.x >> 6;
    if (lane == 0) wsum[wv] = s;
    __syncthreads();
    if (threadIdx.x == 0)
        acc[v] = wsum[0] + wsum[1] + wsum[2] + wsum[3];
}

// ---------------------------------------------------------------------------
// Kernel 3: K deflation iterations in 9-dim coefficient space (fp64).
// Fully unrolled -> G/T/vectors in VGPRs. 64 threads, launch_bounds(64,1)
// so the allocator has the full 512-VGPR budget (proven no-spill config).
// ---------------------------------------------------------------------------
__global__ __launch_bounds__(64, 1) void iterate_kernel(const float* __restrict__ acc,
                                                        const int* __restrict__ Kp,
                                                        float* __restrict__ w_out) {
    double G[MM][MM], s0[MM], T[MM][MM], w[MM];
    #pragma unroll
    for (int m = 0; m < MM; ++m) {
        #pragma unroll
        for (int mm = m; mm < MM; ++mm) {
            double v = (double)acc[tri_idx(m, mm)];
            G[m][mm] = v;
            G[mm][m] = v;
        }
    }
    #pragma unroll
    for (int m = 0; m < MM; ++m) s0[m] = (double)acc[36 + m];
    #pragma unroll
    for (int m = 0; m < MM; ++m) {
        w[m] = 0.0;
        #pragma unroll
        for (int k = 0; k < MM; ++k) T[m][k] = (m == k) ? 1.0 : 0.0;
    }

    const int K = *Kp;
    for (int it = 0; it < K; ++it) {
        double sy[MM];
        #pragma unroll
        for (int k = 0; k < MM; ++k) {
            double a = s0[k];
            #pragma unroll
            for (int j = 0; j < MM; ++j) a += G[k][j] * w[j];
            sy[k] = a;
        }
        double s[MM];
        #pragma unroll
        for (int m = 0; m < MM; ++m) {
            double a = 0.0;
            #pragma unroll
            for (int k = 0; k < MM; ++k) a += T[m][k] * sy[k];
            s[m] = a;
        }
        double c[MM];
        #pragma unroll
        for (int k = 0; k < MM; ++k) {
            double a = 0.0;
            #pragma unroll
            for (int m = 0; m < MM; ++m) a += T[m][k] * s[m];
            c[k] = a;
        }
        double Gc[MM];
        #pragma unroll
        for (int k = 0; k < MM; ++k) {
            double a = 0.0;
            #pragma unroll
            for (int j = 0; j < MM; ++j) a += G[k][j] * c[j];
            Gc[k] = a;
        }
        double den = 0.0, num = 0.0;
        #pragma unroll
        for (int k = 0; k < MM; ++k) den += c[k] * Gc[k];
        #pragma unroll
        for (int m = 0; m < MM; ++m) num += s[m] * s[m];
        const double inv_den = 1.0 / den;
        const double alpha = num * inv_den;
        #pragma unroll
        for (int k = 0; k < MM; ++k) w[k] -= alpha * c[k];
        #pragma unroll
        for (int m = 0; m < MM; ++m) {
            double beta = 0.0;
            #pragma unroll
            for (int k = 0; k < MM; ++k) beta += T[m][k] * Gc[k];
            beta *= inv_den;
            #pragma unroll
            for (int k = 0; k < MM; ++k) T[m][k] -= beta * c[k];
        }
    }
    if (threadIdx.x == 0 && blockIdx.x == 0) {
        #pragma unroll
        for (int k = 0; k < MM; ++k) w_out[k] = (float)w[k];
    }
}

// ---------------------------------------------------------------------------
// Kernel 4: Y += sum_m w_m * A0_m (in place on d_out).
// Same blocked-contiguous partition as gram.
// ---------------------------------------------------------------------------
__global__ __launch_bounds__(256) void reconstruct(const float* __restrict__ A,
                                                   const float* __restrict__ w,
                                                   float* __restrict__ Y) {
    __shared__ float wsh[MM];
    if (threadIdx.x < MM) wsh[threadIdx.x] = w[threadIdx.x];
    __syncthreads();
    float wl[MM];
    #pragma unroll
    for (int m = 0; m < MM; ++m) wl[m] = wsh[m];

    const int P4 = (NN * NN) / 4;
    float4* Y4 = reinterpret_cast<float4*>(Y);
    const float4* A4 = reinterpret_cast<const float4*>(A);
    const int base = blockIdx.x * 512 + threadIdx.x;

    #pragma unroll
    for (int it = 0; it < 2; ++it) {
        const int p = base + it * 256;
        float4 y = Y4[p];
        #pragma unroll
        for (int m = 0; m < MM; ++m) {
            float4 a = A4[m * P4 + p];
            y.x += wl[m] * a.x;
            y.y += wl[m] * a.y;
            y.z += wl[m] * a.z;
            y.w += wl[m] * a.w;
        }
        Y4[p] = y;
    }
}

extern "C" void kernel_launch(void* const* d_in, const int* in_sizes, int n_in,
                              void* d_out, int out_size, void* d_ws, size_t ws_size,
                              hipStream_t stream) {
    const float* X = (const float*)d_in[0];
    const float* A = (const float*)d_in[1];
    const int* Kp = (const int*)d_in[2];
    float* Y = (float*)d_out;

    float* acc = (float*)d_ws;                                 // [0..43]  G0 tri + s0
    float* w = (float*)d_ws + 48;                              // [48..55] w coefficients
    unsigned short* Xhi = (unsigned short*)((char*)d_ws + 4096);
    unsigned short* Xlo = Xhi + NN * DD;                       // 2 MB each
    float* partialT = (float*)((char*)d_ws + (8u << 20));      // [44][2048] floats

    convert_split<<<1024, 256, 0, stream>>>(X, Xhi, Xlo);
    gemm_mfma<<<dim3(16, 16), 256, 0, stream>>>(Xhi, Xlo, Y);
    gram_kernel<<<GRAM_BLOCKS, 256, 0, stream>>>(A, Y, partialT);
    gram_reduce<<<44, 256, 0, stream>>>(partialT, acc);
    iterate_kernel<<<1, 64, 0, stream>>>(acc, Kp, w);
    reconstruct<<<2048, 256, 0, stream>>>(A, w, Y);
}